// Round 2
// baseline (122.904 us; speedup 1.0000x reference)
//
#include <hip/hip_runtime.h>
#include <math.h>

#define H 2048
#define V 50257
#define M 64

#define NEG_BIG (-1.0e30f)

// K5 geometry: 4 waves/block, 13 rows/wave
#define RPW 13
#define NB5 967            // ceil(V / (4*13)) -> 967*52 = 50284 >= 50257
#define NB6 197            // ceil(V / 256)

// ---------- wave-64 sum reduction (lane 0 gets result) ----------
__device__ inline float wred_sum(float v) {
#pragma unroll
    for (int o = 32; o >= 1; o >>= 1) v += __shfl_down(v, o);
    return v;
}

// ---------- K1: attention scores: score[m] = attn_w[m,:] . concat(emb_row, h0) + attn_b[m]
__global__ void k_scores(const int* __restrict__ tok, const float* __restrict__ hidden,
                         const float* __restrict__ emb, const float* __restrict__ attn_w,
                         const float* __restrict__ attn_b, float* __restrict__ scores) {
    const int m = blockIdx.x;         // 64 blocks
    const int t = threadIdx.x;        // 256 threads
    const float* erow = emb + (size_t)tok[0] * H;
    const float4* w4 = (const float4*)(attn_w + (size_t)m * 2 * H);
    float acc = 0.f;
    for (int i = t; i < 1024; i += 256) {
        float4 w = w4[i];
        int k = i * 4;
        float4 c = (k < H) ? *(const float4*)(erow + k)
                           : *(const float4*)(hidden + (k - H));
        acc += w.x * c.x + w.y * c.y + w.z * c.z + w.w * c.w;
    }
    __shared__ float sred[4];
    float s = wred_sum(acc);
    int wid = t >> 6, lane = t & 63;
    if (lane == 0) sred[wid] = s;
    __syncthreads();
    if (t == 0) scores[m] = sred[0] + sred[1] + sred[2] + sred[3] + attn_b[m];
}

// ---------- K2: softmax over 64 scores (wave 0, redundant per block) + attn_applied chunk
__global__ void k_sm_aa(const float* __restrict__ scores, const float* __restrict__ enc,
                        float* __restrict__ aw_out, float* __restrict__ attn_applied) {
    __shared__ float w[M];
    int t = threadIdx.x;
    if (t < 64) {
        float s = scores[t];
        float mx = s;
#pragma unroll
        for (int o = 32; o >= 1; o >>= 1) mx = fmaxf(mx, __shfl_xor(mx, o));
        float e = expf(s - mx);
        float sum = e;
#pragma unroll
        for (int o = 32; o >= 1; o >>= 1) sum += __shfl_xor(sum, o);
        float aw = e / sum;
        w[t] = aw;
        if (blockIdx.x == 0) aw_out[t] = aw;   // attn_weights output
    }
    __syncthreads();
    int h = blockIdx.x * 256 + t;  // 8 blocks x 256 = 2048
    float acc = 0.f;
#pragma unroll 8
    for (int m = 0; m < M; ++m) acc += w[m] * enc[(size_t)m * H + h];
    attn_applied[h] = acc;
}

// ---------- K3: x[r] = relu(comb_w[r,:] . concat(emb_row, attn_applied) + comb_b[r])
__global__ void k_combine(const int* __restrict__ tok, const float* __restrict__ emb,
                          const float* __restrict__ comb_w, const float* __restrict__ comb_b,
                          const float* __restrict__ aa, float* __restrict__ x_out) {
    int r = (blockIdx.x * blockDim.x + threadIdx.x) >> 6;  // 2048 rows, wave per row
    int lane = threadIdx.x & 63;
    const float* erow = emb + (size_t)tok[0] * H;
    const float4* w4 = (const float4*)(comb_w + (size_t)r * 2 * H);
    float acc = 0.f;
#pragma unroll
    for (int it = 0; it < 16; ++it) {
        int i = it * 64 + lane;  // 1024 float4 per row
        float4 w = w4[i];
        int k = i * 4;
        float4 c = (k < H) ? *(const float4*)(erow + k)
                           : *(const float4*)(aa + (k - H));
        acc += w.x * c.x + w.y * c.y + w.z * c.z + w.w * c.w;
    }
    acc = wred_sum(acc);
    if (lane == 0) x_out[r] = fmaxf(acc + comb_b[r], 0.f);
}

// ---------- K4: GRU cell, one wave per output element j
__global__ void k_gru(const float* __restrict__ hidden, const float* __restrict__ w_ih,
                      const float* __restrict__ w_hh, const float* __restrict__ b_ih,
                      const float* __restrict__ b_hh, const float* __restrict__ x,
                      float* __restrict__ h_out) {
    int j = (blockIdx.x * blockDim.x + threadIdx.x) >> 6;  // 2048 rows
    int lane = threadIdx.x & 63;
    const float4* x4 = (const float4*)x;
    const float4* h4 = (const float4*)hidden;
    const float4* wir = (const float4*)(w_ih + (size_t)j * H);
    const float4* wiz = (const float4*)(w_ih + (size_t)(H + j) * H);
    const float4* win = (const float4*)(w_ih + (size_t)(2 * H + j) * H);
    const float4* whr = (const float4*)(w_hh + (size_t)j * H);
    const float4* whz = (const float4*)(w_hh + (size_t)(H + j) * H);
    const float4* whn = (const float4*)(w_hh + (size_t)(2 * H + j) * H);
    float air = 0, aiz = 0, ain = 0, ahr = 0, ahz = 0, ahn = 0;
#pragma unroll
    for (int it = 0; it < 8; ++it) {
        int i = it * 64 + lane;  // 512 float4 per row
        float4 xv = x4[i], hv = h4[i];
        float4 a;
        a = wir[i]; air += a.x * xv.x + a.y * xv.y + a.z * xv.z + a.w * xv.w;
        a = wiz[i]; aiz += a.x * xv.x + a.y * xv.y + a.z * xv.z + a.w * xv.w;
        a = win[i]; ain += a.x * xv.x + a.y * xv.y + a.z * xv.z + a.w * xv.w;
        a = whr[i]; ahr += a.x * hv.x + a.y * hv.y + a.z * hv.z + a.w * hv.w;
        a = whz[i]; ahz += a.x * hv.x + a.y * hv.y + a.z * hv.z + a.w * hv.w;
        a = whn[i]; ahn += a.x * hv.x + a.y * hv.y + a.z * hv.z + a.w * hv.w;
    }
    air = wred_sum(air); aiz = wred_sum(aiz); ain = wred_sum(ain);
    ahr = wred_sum(ahr); ahz = wred_sum(ahz); ahn = wred_sum(ahn);
    if (lane == 0) {
        float r = 1.f / (1.f + expf(-(air + b_ih[j] + ahr + b_hh[j])));
        float z = 1.f / (1.f + expf(-(aiz + b_ih[H + j] + ahz + b_hh[H + j])));
        float n = tanhf(ain + b_ih[2 * H + j] + r * (ahn + b_hh[2 * H + j]));
        h_out[j] = (1.f - z) * n + z * hidden[j];
    }
}

// ---------- K5: logits GEMV (13 rows/wave, h in regs) + per-block online LSE partial
__global__ void k_logits(const float* __restrict__ out_w, const float* __restrict__ out_b,
                         const float* __restrict__ hnew, float* __restrict__ logits,
                         float2* __restrict__ part) {
    const int t = threadIdx.x;
    const int lane = t & 63, wid = t >> 6;
    const int gw = blockIdx.x * 4 + wid;          // global wave id
    const int base = gw * RPW;

    // h_new: 8 float4 registers per lane (lane-strided, whole wave covers 2048 floats)
    const float4* h4 = (const float4*)hnew;
    float4 h[8];
#pragma unroll
    for (int it = 0; it < 8; ++it) h[it] = h4[it * 64 + lane];

    float m = NEG_BIG, s = 0.f;   // lane-0-valid online LSE state
#pragma unroll
    for (int r = 0; r < RPW; ++r) {
        int row = base + r;
        if (row >= V) break;
        const float4* w4 = (const float4*)(out_w + (size_t)row * H);
        float acc = 0.f;
#pragma unroll
        for (int it = 0; it < 8; ++it) {
            float4 w = w4[it * 64 + lane];
            acc += w.x * h[it].x + w.y * h[it].y + w.z * h[it].z + w.w * h[it].w;
        }
        acc = wred_sum(acc);
        if (lane == 0) {
            float lg = acc + out_b[row];
            logits[row] = lg;
            if (lg > m) { s = s * expf(m - lg) + 1.f; m = lg; }
            else s += expf(lg - m);
        }
    }
    // combine 4 waves' (m,s) -> one partial per block
    __shared__ float2 lms[4];
    if (lane == 0) lms[wid] = make_float2(m, s);
    __syncthreads();
    if (t == 0) {
        float gm = NEG_BIG, gs = 0.f;
#pragma unroll
        for (int i = 0; i < 4; ++i) {
            float m2 = lms[i].x, s2 = lms[i].y;
            float mm = fmaxf(gm, m2);
            gs = gs * expf(gm - mm) + s2 * expf(m2 - mm);
            gm = mm;
        }
        part[blockIdx.x] = make_float2(gm, gs);
    }
}

// ---------- K6: reduce NB5 partials (per block, from L2) + in-place log-softmax
__global__ void k_logsoftmax(float* __restrict__ logits, const float2* __restrict__ part) {
    const int t = threadIdx.x;
    float m = NEG_BIG, s = 0.f;
    for (int i = t; i < NB5; i += 256) {
        float2 p = part[i];
        float mm = fmaxf(m, p.x);
        s = s * expf(m - mm) + p.y * expf(p.x - mm);
        m = mm;
    }
    __shared__ float sm[256], ss[256];
    sm[t] = m; ss[t] = s;
    __syncthreads();
    for (int o = 128; o >= 1; o >>= 1) {
        if (t < o) {
            float m2 = sm[t + o], s2 = ss[t + o];
            float mm = fmaxf(sm[t], m2);
            ss[t] = ss[t] * expf(sm[t] - mm) + s2 * expf(m2 - mm);
            sm[t] = mm;
        }
        __syncthreads();
    }
    float lse = sm[0] + logf(ss[0]);
    int i = blockIdx.x * 256 + t;
    if (i < V) logits[i] -= lse;
}

extern "C" void kernel_launch(void* const* d_in, const int* in_sizes, int n_in,
                              void* d_out, int out_size, void* d_ws, size_t ws_size,
                              hipStream_t stream) {
    const int*   tok     = (const int*)d_in[0];
    const float* hidden  = (const float*)d_in[1];   // [1,1,H]
    const float* enc     = (const float*)d_in[2];   // [M,H]
    const float* emb     = (const float*)d_in[3];   // [V,H]
    const float* attn_w  = (const float*)d_in[4];   // [M,2H]
    const float* attn_b  = (const float*)d_in[5];   // [M]
    const float* comb_w  = (const float*)d_in[6];   // [H,2H]
    const float* comb_b  = (const float*)d_in[7];   // [H]
    const float* w_ih    = (const float*)d_in[8];   // [3H,H]
    const float* w_hh    = (const float*)d_in[9];   // [3H,H]
    const float* b_ih    = (const float*)d_in[10];  // [3H]
    const float* b_hh    = (const float*)d_in[11];  // [3H]
    const float* out_w   = (const float*)d_in[12];  // [V,H]
    const float* out_b   = (const float*)d_in[13];  // [V]

    float* out = (float*)d_out;
    float* logp  = out;             // [V]
    float* hout  = out + V;         // [H]
    float* awout = out + V + H;     // [M]

    float* ws   = (float*)d_ws;
    float*  AA   = ws;              // [2048] attn_applied
    float*  X    = ws + 2048;       // [2048] relu(combine)
    float*  SC   = ws + 4096;       // [64]   raw scores
    float2* PART = (float2*)(ws + 4224);  // [NB5] lse partials (16B-aligned ok: 4224*4=16896)

    k_scores    <<<64,  256, 0, stream>>>(tok, hidden, emb, attn_w, attn_b, SC);
    k_sm_aa     <<<8,   256, 0, stream>>>(SC, enc, awout, AA);
    k_combine   <<<512, 256, 0, stream>>>(tok, emb, comb_w, comb_b, AA, X);
    k_gru       <<<512, 256, 0, stream>>>(hidden, w_ih, w_hh, b_ih, b_hh, X, hout);
    k_logits    <<<NB5, 256, 0, stream>>>(out_w, out_b, hout, logp, PART);
    k_logsoftmax<<<NB6, 256, 0, stream>>>(logp, PART);
}

// Round 3
// 106.588 us; speedup vs baseline: 1.1531x; 1.1531x over previous
//
#include <hip/hip_runtime.h>
#include <math.h>

#define H 2048
#define V 50257
#define M 64
#define NEG_BIG (-1.0e30f)

#define NB5 6283   // ceil(V/8): logits blocks, 8 rows/block (2 rows/wave)
#define NB6 197    // ceil(V/256)

typedef float f4 __attribute__((ext_vector_type(4)));

__device__ inline f4 ntload(const f4* p) { return __builtin_nontemporal_load(p); }
__device__ inline float dot4(f4 a, f4 b) { return a.x*b.x + a.y*b.y + a.z*b.z + a.w*b.w; }

__device__ inline float wred_sum(float v) {
#pragma unroll
    for (int o = 32; o >= 1; o >>= 1) v += __shfl_down(v, o);
    return v;  // lane 0 holds the sum
}

// ---------- K1: attention scores (blocks 0..63) + gh rows 0..3071 (blocks 64..831)
// gh[j] = w_hh[j,:] . h0 + b_hh[j]   (depends only on inputs -> overlap with attention chain)
__global__ void k_scores_gh1(const int* __restrict__ tok, const float* __restrict__ hidden,
                             const float* __restrict__ emb, const float* __restrict__ attn_w,
                             const float* __restrict__ attn_b, const float* __restrict__ w_hh,
                             const float* __restrict__ b_hh, float* __restrict__ scores,
                             float* __restrict__ gh) {
    const int t = threadIdx.x, lane = t & 63, wid = t >> 6;
    if (blockIdx.x < 64) {
        const int m = blockIdx.x;
        const float* erow = emb + (size_t)tok[0] * H;
        const f4* w4 = (const f4*)(attn_w + (size_t)m * 2 * H);
        float acc = 0.f;
        for (int i = t; i < 1024; i += 256) {
            f4 w = ntload(w4 + i);
            int k = i * 4;
            f4 c = (k < H) ? *(const f4*)(erow + k) : *(const f4*)(hidden + (k - H));
            acc += dot4(w, c);
        }
        __shared__ float sred[4];
        float s = wred_sum(acc);
        if (lane == 0) sred[wid] = s;
        __syncthreads();
        if (t == 0) scores[m] = sred[0] + sred[1] + sred[2] + sred[3] + attn_b[m];
    } else {
        const int j = (blockIdx.x - 64) * 4 + wid;   // 768 blocks * 4 waves = rows 0..3071
        const f4* w4 = (const f4*)(w_hh + (size_t)j * H);
        const f4* h4 = (const f4*)hidden;
        float acc = 0.f;
#pragma unroll
        for (int it = 0; it < 8; ++it) {
            int i = it * 64 + lane;
            acc += dot4(ntload(w4 + i), h4[i]);
        }
        acc = wred_sum(acc);
        if (lane == 0) gh[j] = acc + b_hh[j];
    }
}

// ---------- K2: softmax(M) + attn_applied (blocks 0..7) + gh rows 3072..6143 (blocks 8..775)
__global__ void k_sm_aa_gh2(const float* __restrict__ scores, const float* __restrict__ enc,
                            const float* __restrict__ hidden, const float* __restrict__ w_hh,
                            const float* __restrict__ b_hh, float* __restrict__ aw_out,
                            float* __restrict__ attn_applied, float* __restrict__ gh) {
    const int t = threadIdx.x, lane = t & 63, wid = t >> 6;
    if (blockIdx.x < 8) {
        __shared__ float w[M];
        if (t < 64) {
            float s = scores[t];
            float mx = s;
#pragma unroll
            for (int o = 32; o >= 1; o >>= 1) mx = fmaxf(mx, __shfl_xor(mx, o));
            float e = expf(s - mx);
            float sum = e;
#pragma unroll
            for (int o = 32; o >= 1; o >>= 1) sum += __shfl_xor(sum, o);
            float aw = e / sum;
            w[t] = aw;
            if (blockIdx.x == 0) aw_out[t] = aw;
        }
        __syncthreads();
        int h = blockIdx.x * 256 + t;  // 8 blocks x 256 = 2048
        float acc = 0.f;
#pragma unroll 8
        for (int m = 0; m < M; ++m) acc += w[m] * enc[(size_t)m * H + h];
        attn_applied[h] = acc;
    } else {
        const int j = 3072 + (blockIdx.x - 8) * 4 + wid;  // 768 blocks -> rows 3072..6143
        const f4* w4 = (const f4*)(w_hh + (size_t)j * H);
        const f4* h4 = (const f4*)hidden;
        float acc = 0.f;
#pragma unroll
        for (int it = 0; it < 8; ++it) {
            int i = it * 64 + lane;
            acc += dot4(ntload(w4 + i), h4[i]);
        }
        acc = wred_sum(acc);
        if (lane == 0) gh[j] = acc + b_hh[j];
    }
}

// ---------- K3: x[r] = relu(comb_w[r,:] . concat(emb_row, attn_applied) + comb_b[r])
__global__ void k_combine(const int* __restrict__ tok, const float* __restrict__ emb,
                          const float* __restrict__ comb_w, const float* __restrict__ comb_b,
                          const float* __restrict__ aa, float* __restrict__ x_out) {
    int r = (blockIdx.x * blockDim.x + threadIdx.x) >> 6;  // 2048 rows, wave per row
    int lane = threadIdx.x & 63;
    const float* erow = emb + (size_t)tok[0] * H;
    const f4* w4 = (const f4*)(comb_w + (size_t)r * 2 * H);
    float acc = 0.f;
#pragma unroll
    for (int it = 0; it < 16; ++it) {
        int i = it * 64 + lane;  // 1024 f4 per row
        f4 w = ntload(w4 + i);
        int k = i * 4;
        f4 c = (k < H) ? *(const f4*)(erow + k) : *(const f4*)(aa + (k - H));
        acc += dot4(w, c);
    }
    acc = wred_sum(acc);
    if (lane == 0) x_out[r] = fmaxf(acc + comb_b[r], 0.f);
}

// ---------- K4: gi = w_ih . x, gates with precomputed gh -> h_new
__global__ void k_gates(const float* __restrict__ hidden, const float* __restrict__ w_ih,
                        const float* __restrict__ b_ih, const float* __restrict__ x,
                        const float* __restrict__ gh, float* __restrict__ h_out) {
    int j = (blockIdx.x * blockDim.x + threadIdx.x) >> 6;  // 2048 rows
    int lane = threadIdx.x & 63;
    const f4* x4 = (const f4*)x;
    const f4* wr = (const f4*)(w_ih + (size_t)j * H);
    const f4* wz = (const f4*)(w_ih + (size_t)(H + j) * H);
    const f4* wn = (const f4*)(w_ih + (size_t)(2 * H + j) * H);
    float ar = 0.f, az = 0.f, an = 0.f;
#pragma unroll
    for (int it = 0; it < 8; ++it) {
        int i = it * 64 + lane;
        f4 xv = x4[i];
        ar += dot4(ntload(wr + i), xv);
        az += dot4(ntload(wz + i), xv);
        an += dot4(ntload(wn + i), xv);
    }
    ar = wred_sum(ar); az = wred_sum(az); an = wred_sum(an);
    if (lane == 0) {
        float r = 1.f / (1.f + expf(-(ar + b_ih[j] + gh[j])));
        float z = 1.f / (1.f + expf(-(az + b_ih[H + j] + gh[H + j])));
        float n = tanhf(an + b_ih[2 * H + j] + r * gh[2 * H + j]);
        h_out[j] = (1.f - z) * n + z * hidden[j];
    }
}

// ---------- K5: logits GEMV, 2 rows/wave fully unrolled + per-block online LSE partial
__global__ void k_logits(const float* __restrict__ out_w, const float* __restrict__ out_b,
                         const float* __restrict__ hnew, float* __restrict__ logits,
                         float2* __restrict__ part) {
    const int t = threadIdx.x, lane = t & 63, wid = t >> 6;
    const int base = (blockIdx.x * 4 + wid) * 2;
    const int row0 = base, row1 = base + 1;
    const bool v0 = row0 < V, v1 = row1 < V;
    const f4* w0 = (const f4*)(out_w + (size_t)(v0 ? row0 : 0) * H);
    const f4* w1 = (const f4*)(out_w + (size_t)(v1 ? row1 : 0) * H);
    const f4* h4 = (const f4*)hnew;
    float a0 = 0.f, a1 = 0.f;
#pragma unroll
    for (int it = 0; it < 8; ++it) {
        int i = it * 64 + lane;
        f4 h = h4[i];                 // L1-resident after first waves
        a0 += dot4(ntload(w0 + i), h);
        a1 += dot4(ntload(w1 + i), h);
    }
    a0 = wred_sum(a0); a1 = wred_sum(a1);
    float m = NEG_BIG, s = 0.f;
    if (lane == 0) {
        if (v0) { float lg = a0 + out_b[row0]; logits[row0] = lg; m = lg; s = 1.f; }
        if (v1) { float lg = a1 + out_b[row1]; logits[row1] = lg;
                  float mm = fmaxf(m, lg); s = s * expf(m - mm) + expf(lg - mm); m = mm; }
    }
    __shared__ float2 lms[4];
    if (lane == 0) lms[wid] = make_float2(m, s);
    __syncthreads();
    if (t == 0) {
        float gm = NEG_BIG, gs = 0.f;
#pragma unroll
        for (int i2 = 0; i2 < 4; ++i2) {
            float m2 = lms[i2].x, s2 = lms[i2].y;
            float mm = fmaxf(gm, m2);
            gs = gs * expf(gm - mm) + s2 * expf(m2 - mm);
            gm = mm;
        }
        part[blockIdx.x] = make_float2(gm, gs);
    }
}

// ---------- K6: reduce NB5 partials (L2-resident) + in-place log-softmax
__global__ void k_logsoftmax(float* __restrict__ logits, const float2* __restrict__ part) {
    const int t = threadIdx.x;
    float m = NEG_BIG, s = 0.f;
    for (int i = t; i < NB5; i += 256) {
        float2 p = part[i];
        float mm = fmaxf(m, p.x);
        s = s * expf(m - mm) + p.y * expf(p.x - mm);
        m = mm;
    }
    __shared__ float sm[256], ss[256];
    sm[t] = m; ss[t] = s;
    __syncthreads();
    for (int o = 128; o >= 1; o >>= 1) {
        if (t < o) {
            float m2 = sm[t + o], s2 = ss[t + o];
            float mm = fmaxf(sm[t], m2);
            ss[t] = ss[t] * expf(sm[t] - mm) + s2 * expf(m2 - mm);
            sm[t] = mm;
        }
        __syncthreads();
    }
    float lse = sm[0] + logf(ss[0]);
    int i = blockIdx.x * 256 + t;
    if (i < V) logits[i] -= lse;
}

extern "C" void kernel_launch(void* const* d_in, const int* in_sizes, int n_in,
                              void* d_out, int out_size, void* d_ws, size_t ws_size,
                              hipStream_t stream) {
    const int*   tok     = (const int*)d_in[0];
    const float* hidden  = (const float*)d_in[1];   // [1,1,H]
    const float* enc     = (const float*)d_in[2];   // [M,H]
    const float* emb     = (const float*)d_in[3];   // [V,H]
    const float* attn_w  = (const float*)d_in[4];   // [M,2H]
    const float* attn_b  = (const float*)d_in[5];   // [M]
    const float* comb_w  = (const float*)d_in[6];   // [H,2H]
    const float* comb_b  = (const float*)d_in[7];   // [H]
    const float* w_ih    = (const float*)d_in[8];   // [3H,H]
    const float* w_hh    = (const float*)d_in[9];   // [3H,H]
    const float* b_ih    = (const float*)d_in[10];  // [3H]
    const float* b_hh    = (const float*)d_in[11];  // [3H]
    const float* out_w   = (const float*)d_in[12];  // [V,H]
    const float* out_b   = (const float*)d_in[13];  // [V]

    float* out = (float*)d_out;
    float* logp  = out;             // [V]
    float* hout  = out + V;         // [H]
    float* awout = out + V + H;     // [M]

    float* ws = (float*)d_ws;
    float*  AA   = ws;                      // [2048] attn_applied
    float*  X    = ws + 2048;               // [2048] relu(combine)
    float*  SC   = ws + 4096;               // [64]   raw scores
    float*  GH   = ws + 4160;               // [6144] gh = w_hh.h0 + b_hh
    float2* PART = (float2*)(ws + 10304);   // [NB5]  lse partials (8B-aligned)

    k_scores_gh1<<<832, 256, 0, stream>>>(tok, hidden, emb, attn_w, attn_b, w_hh, b_hh, SC, GH);
    k_sm_aa_gh2 <<<776, 256, 0, stream>>>(SC, enc, hidden, w_hh, b_hh, awout, AA, GH);
    k_combine   <<<512, 256, 0, stream>>>(tok, emb, comb_w, comb_b, AA, X);
    k_gates     <<<512, 256, 0, stream>>>(hidden, w_ih, b_ih, X, GH, hout);
    k_logits    <<<NB5, 256, 0, stream>>>(out_w, out_b, hout, logp, PART);
    k_logsoftmax<<<NB6, 256, 0, stream>>>(logp, PART);
}